// Round 1
// baseline (849.498 us; speedup 1.0000x reference)
//
#include <hip/hip_runtime.h>
#include <hip/hip_bf16.h>
#include <stdint.h>

#define SEQ 2048
#define DIM 1024
#define NB  8

typedef __attribute__((ext_vector_type(8))) __bf16 bf16x8;
typedef __attribute__((ext_vector_type(8))) unsigned short ushort8;
typedef __attribute__((ext_vector_type(4))) float f32x4;

__device__ inline unsigned short f2b(float f) {
  union { float f; uint32_t u; } c; c.f = f;
  uint32_t u = c.u;
  return (unsigned short)((u + 0x7fffu + ((u >> 16) & 1u)) >> 16);
}

__device__ inline void async16(const void* g, void* l) {
  __builtin_amdgcn_global_load_lds((const __attribute__((address_space(1))) uint32_t*)g,
                                   (__attribute__((address_space(3))) uint32_t*)l,
                                   16, 0, 0);
}

// fp32 -> bf16 cast, vectorized x4
__global__ __launch_bounds__(256) void cvt_f32_bf16(const float* __restrict__ in,
                                                    unsigned short* __restrict__ out, int n4) {
  int idx = blockIdx.x * 256 + threadIdx.x;
  int stride = gridDim.x * 256;
  for (int i = idx; i < n4; i += stride) {
    float4 f = ((const float4*)in)[i];
    ushort4 h;
    h.x = f2b(f.x); h.y = f2b(f.y); h.z = f2b(f.z); h.w = f2b(f.w);
    ((ushort4*)out)[i] = h;
  }
}

// NT GEMM: C[m,n] = sum_k A[m,k]*B[n,k]. 128x128 tile, BK=32, 4 waves (2x2), 4x4 MFMA frags/wave.
// MODE 0: proj   — C bf16, + bias[col]
// MODE 1: scores — C fp32 * scale, skip blocks fully above diagonal (blockIdx.y > blockIdx.x)
// MODE 2: PV     — C fp32, K capped at bm0+128 (causal: attn rows have zeros past row idx)
template<int MODE>
__global__ __launch_bounds__(256)
void gemm_nt(const unsigned short* __restrict__ A,
             const unsigned short* __restrict__ B,
             void* __restrict__ Cv,
             const float* __restrict__ bias,
             int K, int lda, int ldb, int ldc,
             long long aStride, long long bStride, long long cStride,
             float scale)
{
  if (MODE == 1 && blockIdx.y > blockIdx.x) return;
  __shared__ __align__(16) unsigned short lA[128 * 32];
  __shared__ __align__(16) unsigned short lB[128 * 32];
  const int bm0 = blockIdx.x * 128;
  const int bn0 = blockIdx.y * 128;
  const int z = blockIdx.z;
  A += (long long)z * aStride;
  B += (long long)z * bStride;
  const int tid  = threadIdx.x;
  const int lane = tid & 63;
  const int wv   = tid >> 6;
  const int wm   = (wv >> 1) * 64;
  const int wn   = (wv & 1) * 64;
  const int l15  = lane & 15;
  const int l4   = lane >> 4;
  const int Keff = (MODE == 2) ? (bm0 + 128) : K;

  f32x4 acc[4][4] = {};

  const int srow = tid >> 2;          // 0..63: row within tile (per 4KB issue)
  const int skb  = (tid & 3) * 16;    // byte offset within 64B row chunk
  const char* gA = (const char*)A + ((size_t)(bm0 + srow) * lda) * 2 + skb;
  const char* gB = (const char*)B + ((size_t)(bn0 + srow) * ldb) * 2 + skb;
  const size_t stepA = (size_t)64 * lda * 2;
  const size_t stepB = (size_t)64 * ldb * 2;

  for (int k0 = 0; k0 < Keff; k0 += 32) {
    const char* ga = gA + (size_t)k0 * 2;
    const char* gb = gB + (size_t)k0 * 2;
    async16(ga,         &lA[tid * 8]);
    async16(ga + stepA, &lA[(tid + 256) * 8]);
    async16(gb,         &lB[tid * 8]);
    async16(gb + stepB, &lB[(tid + 256) * 8]);
    __syncthreads();
    bf16x8 af[4], bfr[4];
    #pragma unroll
    for (int i = 0; i < 4; ++i)
      af[i] = __builtin_bit_cast(bf16x8, *(const ushort8*)&lA[(wm + i*16 + l15) * 32 + l4 * 8]);
    #pragma unroll
    for (int j = 0; j < 4; ++j)
      bfr[j] = __builtin_bit_cast(bf16x8, *(const ushort8*)&lB[(wn + j*16 + l15) * 32 + l4 * 8]);
    #pragma unroll
    for (int i = 0; i < 4; ++i)
      #pragma unroll
      for (int j = 0; j < 4; ++j)
        acc[i][j] = __builtin_amdgcn_mfma_f32_16x16x32_bf16(af[i], bfr[j], acc[i][j], 0, 0, 0);
    __syncthreads();
  }

  // C/D layout (verified m89/m91): col = lane&15, row = (lane>>4)*4 + reg
  if (MODE == 0) {
    unsigned short* Ch = (unsigned short*)Cv;
    #pragma unroll
    for (int i = 0; i < 4; ++i)
      #pragma unroll
      for (int r = 0; r < 4; ++r) {
        int row = bm0 + wm + i * 16 + l4 * 4 + r;
        #pragma unroll
        for (int j = 0; j < 4; ++j) {
          int col = bn0 + wn + j * 16 + l15;
          Ch[(size_t)row * ldc + col] = f2b(acc[i][j][r] + bias[col]);
        }
      }
  } else {
    float* Cf = (float*)Cv + (long long)z * cStride;
    #pragma unroll
    for (int i = 0; i < 4; ++i)
      #pragma unroll
      for (int r = 0; r < 4; ++r) {
        int row = bm0 + wm + i * 16 + l4 * 4 + r;
        #pragma unroll
        for (int j = 0; j < 4; ++j) {
          int col = bn0 + wn + j * 16 + l15;
          Cf[(size_t)row * ldc + col] = acc[i][j][r] * scale;
        }
      }
  }
}

// per-row causal softmax, in-place fp32 + bf16 copy. One block (256 thr) per row; row fits in 8 regs/thread.
__global__ __launch_bounds__(256)
void softmax_causal(float* __restrict__ attnF, unsigned short* __restrict__ attnH) {
  const int S = SEQ;
  int row = blockIdx.x;            // b*S + i
  int i = row & (S - 1);
  float* rp = attnF + (size_t)row * S;
  unsigned short* hp = attnH + (size_t)row * S;
  int len = i + 1;
  int tid = threadIdx.x;
  float vals[8];
  float m = -1e30f;
  #pragma unroll
  for (int it = 0; it < 8; ++it) {
    int j = it * 256 + tid;
    float v = (j < len) ? rp[j] : -1e30f;
    vals[it] = v;
    m = fmaxf(m, v);
  }
  #pragma unroll
  for (int o = 32; o > 0; o >>= 1) m = fmaxf(m, __shfl_xor(m, o, 64));
  __shared__ float red[4];
  int wv = tid >> 6, lane = tid & 63;
  if (lane == 0) red[wv] = m;
  __syncthreads();
  m = fmaxf(fmaxf(red[0], red[1]), fmaxf(red[2], red[3]));
  __syncthreads();
  float s = 0.f;
  #pragma unroll
  for (int it = 0; it < 8; ++it) {
    float e = __expf(vals[it] - m);   // masked lanes: exp(-1e30) -> 0
    vals[it] = e;
    s += e;
  }
  #pragma unroll
  for (int o = 32; o > 0; o >>= 1) s += __shfl_xor(s, o, 64);
  if (lane == 0) red[wv] = s;
  __syncthreads();
  s = red[0] + red[1] + red[2] + red[3];
  float inv = 1.f / s;
  #pragma unroll
  for (int it = 0; it < 8; ++it) {
    float o = vals[it] * inv;
    rp[it * 256 + tid] = o;
    hp[it * 256 + tid] = f2b(o);
  }
}

// per-batch transpose [SEQ][DIM] -> [DIM][SEQ] (bf16)
__global__ void transpose_bf16(const unsigned short* __restrict__ in, unsigned short* __restrict__ out) {
  __shared__ unsigned short tile[32][33];
  size_t zoff = (size_t)blockIdx.z * SEQ * DIM;
  const unsigned short* ip = in + zoff;
  unsigned short* op = out + zoff;
  int c0 = blockIdx.x * 32;
  int r0 = blockIdx.y * 32;
  int tx = threadIdx.x, ty = threadIdx.y;   // (32,8)
  #pragma unroll
  for (int dy = 0; dy < 32; dy += 8)
    tile[ty + dy][tx] = ip[(size_t)(r0 + ty + dy) * DIM + c0 + tx];
  __syncthreads();
  #pragma unroll
  for (int dy = 0; dy < 32; dy += 8)
    op[(size_t)(c0 + ty + dy) * SEQ + r0 + tx] = tile[tx][ty + dy];
}

extern "C" void kernel_launch(void* const* d_in, const int* in_sizes, int n_in,
                              void* d_out, int out_size, void* d_ws, size_t ws_size,
                              hipStream_t stream) {
  (void)in_sizes; (void)n_in; (void)out_size; (void)ws_size;
  const int B = NB, S = SEQ, D = DIM;
  const size_t BSD = (size_t)B * S * D;   // 16,777,216
  const size_t BSS = (size_t)B * S * S;   // 33,554,432
  const size_t DD  = (size_t)D * D;

  const float* q  = (const float*)d_in[0];
  const float* k  = (const float*)d_in[1];
  const float* v  = (const float*)d_in[2];
  const float* Wq = (const float*)d_in[3];
  const float* bq = (const float*)d_in[4];
  const float* Wk = (const float*)d_in[5];
  const float* bk = (const float*)d_in[6];
  const float* Wv = (const float*)d_in[7];
  const float* bv = (const float*)d_in[8];

  float* out   = (float*)d_out;       // [B,S,D]
  float* attnF = out + BSD;           // [B,S,S]

  // ws layout (ushort elems): xb(BSD) | Wqb(DD) Wkb(DD) Wvb(DD) | qp(BSD) | kp(BSD) | vp/attnH(BSS)
  unsigned short* xb  = (unsigned short*)d_ws;        // bf16 input scratch, later vpT
  unsigned short* Wqb = xb + BSD;
  unsigned short* Wkb = Wqb + DD;
  unsigned short* Wvb = Wkb + DD;
  unsigned short* qp  = Wvb + DD;
  unsigned short* kp  = qp + BSD;
  unsigned short* vp  = kp + BSD;
  unsigned short* attnH = vp;                          // overlaps vp (vp dead after transpose)

  dim3 blk(256);
  // cast weights
  cvt_f32_bf16<<<dim3(512), blk, 0, stream>>>(Wq, Wqb, (int)(DD / 4));
  cvt_f32_bf16<<<dim3(512), blk, 0, stream>>>(Wk, Wkb, (int)(DD / 4));
  cvt_f32_bf16<<<dim3(512), blk, 0, stream>>>(Wv, Wvb, (int)(DD / 4));
  // projections (xb reused serially; stream-ordered)
  cvt_f32_bf16<<<dim3(4096), blk, 0, stream>>>(q, xb, (int)(BSD / 4));
  gemm_nt<0><<<dim3(128, 8, 1), blk, 0, stream>>>(xb, Wqb, qp, bq, D, D, D, D, 0, 0, 0, 1.f);
  cvt_f32_bf16<<<dim3(4096), blk, 0, stream>>>(k, xb, (int)(BSD / 4));
  gemm_nt<0><<<dim3(128, 8, 1), blk, 0, stream>>>(xb, Wkb, kp, bk, D, D, D, D, 0, 0, 0, 1.f);
  cvt_f32_bf16<<<dim3(4096), blk, 0, stream>>>(v, xb, (int)(BSD / 4));
  gemm_nt<0><<<dim3(128, 8, 1), blk, 0, stream>>>(xb, Wvb, vp, bv, D, D, D, D, 0, 0, 0, 1.f);
  // vp -> vpT (into xb)
  transpose_bf16<<<dim3(D / 32, S / 32, B), dim3(32, 8), 0, stream>>>(vp, xb);
  // scores: attnF = qp @ kp^T / 32 (lower-triangular blocks only)
  gemm_nt<1><<<dim3(S / 128, S / 128, B), blk, 0, stream>>>(qp, kp, attnF, nullptr,
      D, D, D, S, (long long)S * D, (long long)S * D, (long long)S * S, 1.f / 32.f);
  // softmax (in-place fp32, bf16 copy to attnH)
  softmax_causal<<<dim3(B * S), blk, 0, stream>>>(attnF, attnH);
  // out = attn @ vp  (B operand is vpT, NT; K capped per row-block)
  gemm_nt<2><<<dim3(S / 128, D / 128, B), blk, 0, stream>>>(attnH, xb, out, nullptr,
      S, S, S, D, (long long)S * S, (long long)D * S, (long long)S * D, 1.f);
}

// Round 2
// 768.096 us; speedup vs baseline: 1.1060x; 1.1060x over previous
//
#include <hip/hip_runtime.h>
#include <hip/hip_bf16.h>
#include <stdint.h>

#define SEQ 2048
#define DIM 1024
#define NB  8

typedef __attribute__((ext_vector_type(8))) __bf16 bf16x8;
typedef __attribute__((ext_vector_type(8))) unsigned short ushort8;
typedef __attribute__((ext_vector_type(4))) float f32x4;

__device__ inline unsigned short f2b(float f) {
  union { float f; uint32_t u; } c; c.f = f;
  uint32_t u = c.u;
  return (unsigned short)((u + 0x7fffu + ((u >> 16) & 1u)) >> 16);
}

__device__ inline void async16(const void* g, void* l) {
  __builtin_amdgcn_global_load_lds((const __attribute__((address_space(1))) uint32_t*)g,
                                   (__attribute__((address_space(3))) uint32_t*)l,
                                   16, 0, 0);
}

// fp32 -> bf16 cast, vectorized x4
__global__ __launch_bounds__(256) void cvt_f32_bf16(const float* __restrict__ in,
                                                    unsigned short* __restrict__ out, int n4) {
  int idx = blockIdx.x * 256 + threadIdx.x;
  int stride = gridDim.x * 256;
  for (int i = idx; i < n4; i += stride) {
    float4 f = ((const float4*)in)[i];
    ushort4 h;
    h.x = f2b(f.x); h.y = f2b(f.y); h.z = f2b(f.z); h.w = f2b(f.w);
    ((ushort4*)out)[i] = h;
  }
}

// L2-locality swizzle: groups of GM=8 M-tiles, N fastest within a group, so
// dispatch-adjacent blocks (which spread round-robin over XCDs) reuse a compact
// ~2MB A-tile set + ~2MB B-tile set that fits one XCD's 4MB L2.
__device__ inline void remap_mn(int& bm, int& bn) {
  const int mT = gridDim.x, nT = gridDim.y;
  int did = blockIdx.y * mT + blockIdx.x;    // dispatch order: x fastest
  const int GM = 8;                           // mT is always a multiple of 8 here
  int per = GM * nT;
  int group = did / per;
  int rem = did - group * per;
  bm = group * GM + (rem % GM);
  bn = rem / GM;
}

// NT GEMM: C[m,n] = sum_k A[m,k]*B[n,k]. 128x128 tile, BK=32, 4 waves (2x2),
// 4x4 MFMA frags/wave. Double-buffered LDS: ONE barrier per K-iter; tile k+1's
// global_load_lds issued before computing tile k (latency hidden behind MFMA).
// MODE 0: proj   — C bf16, + bias[col]
// MODE 1: scores — C fp32 * scale, skip blocks above diagonal
// MODE 2: PV     — C fp32, K capped at bm0+128 (causal zeros beyond)
template<int MODE>
__global__ __launch_bounds__(256)
void gemm_nt(const unsigned short* __restrict__ A,
             const unsigned short* __restrict__ B,
             void* __restrict__ Cv,
             const float* __restrict__ bias,
             int K, int lda, int ldb, int ldc,
             long long aStride, long long bStride, long long cStride,
             float scale)
{
  __shared__ __align__(16) unsigned short lA[2][128 * 32];
  __shared__ __align__(16) unsigned short lB[2][128 * 32];
  int bm, bn;
  remap_mn(bm, bn);
  if (MODE == 1 && bn > bm) return;
  const int bm0 = bm * 128;
  const int bn0 = bn * 128;
  const int z = blockIdx.z;
  A += (long long)z * aStride;
  B += (long long)z * bStride;
  const int tid  = threadIdx.x;
  const int lane = tid & 63;
  const int wv   = tid >> 6;
  const int wm   = (wv >> 1) * 64;
  const int wn   = (wv & 1) * 64;
  const int l15  = lane & 15;
  const int l4   = lane >> 4;
  const int Keff = (MODE == 2) ? (bm0 + 128) : K;

  f32x4 acc[4][4] = {};

  const int srow = tid >> 2;          // 0..63: row within tile
  const int skb  = (tid & 3) * 16;    // byte offset within 64B row chunk
  const char* gA = (const char*)A + ((size_t)(bm0 + srow) * lda) * 2 + skb;
  const char* gB = (const char*)B + ((size_t)(bn0 + srow) * ldb) * 2 + skb;
  const size_t stepA = (size_t)64 * lda * 2;
  const size_t stepB = (size_t)64 * ldb * 2;

  auto stage = [&](int buf, int k0) {
    const char* ga = gA + (size_t)k0 * 2;
    const char* gb = gB + (size_t)k0 * 2;
    async16(ga,         &lA[buf][tid * 8]);
    async16(ga + stepA, &lA[buf][(tid + 256) * 8]);
    async16(gb,         &lB[buf][tid * 8]);
    async16(gb + stepB, &lB[buf][(tid + 256) * 8]);
  };

  stage(0, 0);
  int buf = 0;
  for (int k0 = 0; k0 < Keff; k0 += 32) {
    __syncthreads();                      // vmcnt(0) drain: buf staged; prev reads of buf^1 done
    if (k0 + 32 < Keff) stage(buf ^ 1, k0 + 32);   // in flight during compute below
    bf16x8 af[4], bfr[4];
    #pragma unroll
    for (int i = 0; i < 4; ++i)
      af[i] = __builtin_bit_cast(bf16x8, *(const ushort8*)&lA[buf][(wm + i*16 + l15) * 32 + l4 * 8]);
    #pragma unroll
    for (int j = 0; j < 4; ++j)
      bfr[j] = __builtin_bit_cast(bf16x8, *(const ushort8*)&lB[buf][(wn + j*16 + l15) * 32 + l4 * 8]);
    #pragma unroll
    for (int i = 0; i < 4; ++i)
      #pragma unroll
      for (int j = 0; j < 4; ++j)
        acc[i][j] = __builtin_amdgcn_mfma_f32_16x16x32_bf16(af[i], bfr[j], acc[i][j], 0, 0, 0);
    buf ^= 1;
  }

  // C/D layout (verified m89/m91): col = lane&15, row = (lane>>4)*4 + reg
  if (MODE == 0) {
    unsigned short* Ch = (unsigned short*)Cv;
    #pragma unroll
    for (int i = 0; i < 4; ++i)
      #pragma unroll
      for (int r = 0; r < 4; ++r) {
        int row = bm0 + wm + i * 16 + l4 * 4 + r;
        #pragma unroll
        for (int j = 0; j < 4; ++j) {
          int col = bn0 + wn + j * 16 + l15;
          Ch[(size_t)row * ldc + col] = f2b(acc[i][j][r] + bias[col]);
        }
      }
  } else {
    float* Cf = (float*)Cv + (long long)z * cStride;
    #pragma unroll
    for (int i = 0; i < 4; ++i)
      #pragma unroll
      for (int r = 0; r < 4; ++r) {
        int row = bm0 + wm + i * 16 + l4 * 4 + r;
        #pragma unroll
        for (int j = 0; j < 4; ++j) {
          int col = bn0 + wn + j * 16 + l15;
          Cf[(size_t)row * ldc + col] = acc[i][j][r] * scale;
        }
      }
  }
}

// per-row causal softmax, in-place fp32 + bf16 copy. One block (256 thr) per row.
__global__ __launch_bounds__(256)
void softmax_causal(float* __restrict__ attnF, unsigned short* __restrict__ attnH) {
  const int S = SEQ;
  int row = blockIdx.x;            // b*S + i
  int i = row & (S - 1);
  float* rp = attnF + (size_t)row * S;
  unsigned short* hp = attnH + (size_t)row * S;
  int len = i + 1;
  int tid = threadIdx.x;
  float vals[8];
  float m = -1e30f;
  #pragma unroll
  for (int it = 0; it < 8; ++it) {
    int j = it * 256 + tid;
    float v = (j < len) ? rp[j] : -1e30f;
    vals[it] = v;
    m = fmaxf(m, v);
  }
  #pragma unroll
  for (int o = 32; o > 0; o >>= 1) m = fmaxf(m, __shfl_xor(m, o, 64));
  __shared__ float red[4];
  int wv = tid >> 6, lane = tid & 63;
  if (lane == 0) red[wv] = m;
  __syncthreads();
  m = fmaxf(fmaxf(red[0], red[1]), fmaxf(red[2], red[3]));
  __syncthreads();
  float s = 0.f;
  #pragma unroll
  for (int it = 0; it < 8; ++it) {
    float e = __expf(vals[it] - m);   // masked lanes: exp(-1e30) -> 0
    vals[it] = e;
    s += e;
  }
  #pragma unroll
  for (int o = 32; o > 0; o >>= 1) s += __shfl_xor(s, o, 64);
  if (lane == 0) red[wv] = s;
  __syncthreads();
  s = red[0] + red[1] + red[2] + red[3];
  float inv = 1.f / s;
  #pragma unroll
  for (int it = 0; it < 8; ++it) {
    float o = vals[it] * inv;
    rp[it * 256 + tid] = o;
    hp[it * 256 + tid] = f2b(o);
  }
}

// per-batch transpose [SEQ][DIM] -> [DIM][SEQ] (bf16)
__global__ void transpose_bf16(const unsigned short* __restrict__ in, unsigned short* __restrict__ out) {
  __shared__ unsigned short tile[32][33];
  size_t zoff = (size_t)blockIdx.z * SEQ * DIM;
  const unsigned short* ip = in + zoff;
  unsigned short* op = out + zoff;
  int c0 = blockIdx.x * 32;
  int r0 = blockIdx.y * 32;
  int tx = threadIdx.x, ty = threadIdx.y;   // (32,8)
  #pragma unroll
  for (int dy = 0; dy < 32; dy += 8)
    tile[ty + dy][tx] = ip[(size_t)(r0 + ty + dy) * DIM + c0 + tx];
  __syncthreads();
  #pragma unroll
  for (int dy = 0; dy < 32; dy += 8)
    op[(size_t)(c0 + ty + dy) * SEQ + r0 + tx] = tile[tx][ty + dy];
}

extern "C" void kernel_launch(void* const* d_in, const int* in_sizes, int n_in,
                              void* d_out, int out_size, void* d_ws, size_t ws_size,
                              hipStream_t stream) {
  (void)in_sizes; (void)n_in; (void)out_size; (void)ws_size;
  const int B = NB, S = SEQ, D = DIM;
  const size_t BSD = (size_t)B * S * D;   // 16,777,216
  const size_t BSS = (size_t)B * S * S;   // 33,554,432
  const size_t DD  = (size_t)D * D;

  const float* q  = (const float*)d_in[0];
  const float* k  = (const float*)d_in[1];
  const float* v  = (const float*)d_in[2];
  const float* Wq = (const float*)d_in[3];
  const float* bq = (const float*)d_in[4];
  const float* Wk = (const float*)d_in[5];
  const float* bk = (const float*)d_in[6];
  const float* Wv = (const float*)d_in[7];
  const float* bv = (const float*)d_in[8];

  float* out   = (float*)d_out;       // [B,S,D]
  float* attnF = out + BSD;           // [B,S,S]

  // ws layout (ushort elems): xb(BSD) | Wqb(DD) Wkb(DD) Wvb(DD) | qp(BSD) | kp(BSD) | vp/attnH(BSS)
  unsigned short* xb  = (unsigned short*)d_ws;        // bf16 input scratch, later vpT
  unsigned short* Wqb = xb + BSD;
  unsigned short* Wkb = Wqb + DD;
  unsigned short* Wvb = Wkb + DD;
  unsigned short* qp  = Wvb + DD;
  unsigned short* kp  = qp + BSD;
  unsigned short* vp  = kp + BSD;
  unsigned short* attnH = vp;                          // overlaps vp (vp dead after transpose)

  dim3 blk(256);
  // cast weights
  cvt_f32_bf16<<<dim3(512), blk, 0, stream>>>(Wq, Wqb, (int)(DD / 4));
  cvt_f32_bf16<<<dim3(512), blk, 0, stream>>>(Wk, Wkb, (int)(DD / 4));
  cvt_f32_bf16<<<dim3(512), blk, 0, stream>>>(Wv, Wvb, (int)(DD / 4));
  // projections (xb reused serially; stream-ordered)
  cvt_f32_bf16<<<dim3(4096), blk, 0, stream>>>(q, xb, (int)(BSD / 4));
  gemm_nt<0><<<dim3(128, 8, 1), blk, 0, stream>>>(xb, Wqb, qp, bq, D, D, D, D, 0, 0, 0, 1.f);
  cvt_f32_bf16<<<dim3(4096), blk, 0, stream>>>(k, xb, (int)(BSD / 4));
  gemm_nt<0><<<dim3(128, 8, 1), blk, 0, stream>>>(xb, Wkb, kp, bk, D, D, D, D, 0, 0, 0, 1.f);
  cvt_f32_bf16<<<dim3(4096), blk, 0, stream>>>(v, xb, (int)(BSD / 4));
  gemm_nt<0><<<dim3(128, 8, 1), blk, 0, stream>>>(xb, Wvb, vp, bv, D, D, D, D, 0, 0, 0, 1.f);
  // vp -> vpT (into xb)
  transpose_bf16<<<dim3(D / 32, S / 32, B), dim3(32, 8), 0, stream>>>(vp, xb);
  // scores: attnF = qp @ kp^T / 32 (lower-triangular blocks only)
  gemm_nt<1><<<dim3(S / 128, S / 128, B), blk, 0, stream>>>(qp, kp, attnF, nullptr,
      D, D, D, S, (long long)S * D, (long long)S * D, (long long)S * S, 1.f / 32.f);
  // softmax (in-place fp32, bf16 copy to attnH)
  softmax_causal<<<dim3(B * S), blk, 0, stream>>>(attnF, attnH);
  // out = attn @ vp  (B operand is vpT, NT; K capped per row-block)
  gemm_nt<2><<<dim3(S / 128, D / 128, B), blk, 0, stream>>>(attnH, xb, out, nullptr,
      S, S, S, D, (long long)S * S, (long long)D * S, (long long)S * D, 1.f);
}